// Round 13
// baseline (788.882 us; speedup 1.0000x reference)
//
#include <hip/hip_runtime.h>
#include <hip/hip_bf16.h>
#include <math.h>

#define B_  2048
#define E_  64
#define H_  512
#define T_  20

typedef _Float16 half8 __attribute__((ext_vector_type(8)));
typedef __attribute__((ext_vector_type(4))) float f32x4;
typedef unsigned long long u64;

#define mf16(a, b, c) __builtin_amdgcn_mfma_f32_16x16x32_f16(a, b, c, 0, 0, 0)

__device__ __forceinline__ float sigmoidf_(float x) {
  return 1.0f / (1.0f + __expf(-x));
}
__device__ __forceinline__ float tanh_fast(float x) {
  float e = __expf(2.0f * x);
  return 1.0f - 2.0f / (e + 1.0f);
}

// ---------------------------------------------------------------------------
// Parallel stable counting sort + inverse perm + zero flag areas (4096 ints).
// ---------------------------------------------------------------------------
__global__ __launch_bounds__(256) void k_setup(const int* __restrict__ data,
                                               const int* __restrict__ st,
                                               int* __restrict__ perm,
                                               int* __restrict__ iperm,
                                               int* __restrict__ Mt,
                                               int* __restrict__ flags) {
  __shared__ int lens[B_];
  __shared__ int hist[256][22];
  __shared__ int sub[16][22];
  __shared__ int subpre[16][22];
  __shared__ int cnt[32];
  __shared__ int offs[32];
  int tid = threadIdx.x;

  #pragma unroll
  for (int i = 0; i < 16; ++i) flags[tid * 16 + i] = 0;

  #pragma unroll
  for (int q = 0; q < 8; ++q) {
    int i = tid * 8 + q;
    lens[i] = st[data[i] * (T_ + 1) + T_];
  }
  #pragma unroll
  for (int L = 0; L < 22; ++L) hist[tid][L] = 0;
  #pragma unroll
  for (int q = 0; q < 8; ++q) hist[tid][lens[tid * 8 + q]]++;
  __syncthreads();

  for (int q = tid; q < 16 * 21; q += 256) {
    int g = q / 21, L = q % 21;
    int run = 0;
    for (int j = 0; j < 16; ++j) {
      int v = hist[g * 16 + j][L];
      hist[g * 16 + j][L] = run;
      run += v;
    }
    sub[g][L] = run;
  }
  __syncthreads();
  if (tid < 21) {
    int run = 0;
    for (int g = 0; g < 16; ++g) { subpre[g][tid] = run; run += sub[g][tid]; }
    cnt[tid] = run;
  }
  __syncthreads();
  if (tid <= 20) {
    int s = 0;
    for (int L = tid + 1; L <= 20; ++L) s += cnt[L];
    offs[tid] = s;
  }
  __syncthreads();
  if (tid < T_) Mt[tid] = offs[tid];
  if (tid >= T_ && tid < 32) Mt[tid] = 0;

  int g = tid >> 4;
  #pragma unroll
  for (int q = 0; q < 8; ++q) {
    int i = tid * 8 + q;
    int L = lens[i];
    int rk = subpre[g][L] + hist[tid][L];
    hist[tid][L] += 1;
    perm[offs[L] + rk] = i;
  }
  __syncthreads();
  #pragma unroll
  for (int q = 0; q < 8; ++q) {
    int i = tid * 8 + q;
    iperm[perm[i]] = i;
  }
}

__global__ void k_schars(const int* __restrict__ data, const int* __restrict__ st,
                         const int* __restrict__ perm, int* __restrict__ schars_T) {
  int idx = blockIdx.x * 256 + threadIdx.x;
  if (idx >= B_ * T_) return;
  int t = idx >> 11;
  int j = idx & (B_ - 1);
  schars_T[idx] = st[data[perm[j]] * (T_ + 1) + t];
}

// W -> fp16 fragment-packed (18-chunk r8 layout): Wp[(((cb*18+c)*4+w)*3+g)*512+l*8+e]
__global__ void k_wconv(const float* __restrict__ W_ih, const float* __restrict__ W_hh,
                        _Float16* __restrict__ Wp) {
  int idx = blockIdx.x * 256 + threadIdx.x;
  if (idx >= 8 * 18 * 12 * 512) return;
  int e = idx & 7;
  int l = (idx >> 3) & 63;
  int rest = idx >> 9;
  int g = rest % 3;  rest /= 3;
  int w = rest & 3;  rest >>= 2;
  int c = rest % 18;
  int cb = rest / 18;
  int grow = g * H_ + cb * 64 + w * 16 + (l & 15);
  int k = c * 32 + (l >> 4) * 8 + e;
  float v = (k < E_) ? W_ih[grow * E_ + k] : W_hh[grow * H_ + (k - E_)];
  Wp[idx] = (_Float16)v;
}

__global__ void k_embconv(const float* __restrict__ emb, _Float16* __restrict__ embp) {
  int idx = blockIdx.x * 256 + threadIdx.x;
  if (idx >= 128 * E_) return;
  embp[idx] = (_Float16)emb[idx];
}

// ---------------------------------------------------------------------------
// Round-8 persistent GRU as template<MODE> for within-round ablation.
// MODE 0: real (round-8 exact; writes `out`).
// MODE 1: no staging loads (sb=0); keeps stores+drain+flags+spins.  [scratch]
// MODE 2: no spins; keeps loads+stores+drain+flag stores.           [scratch]
// MODE 3: plain (non-atomic) loads/stores, no spins/atomics.        [scratch]
// MODE 4: compute floor: no loads/stores/flags; LDS+MFMA+epilogue.  [scratch]
// ---------------------------------------------------------------------------
template <int MODE>
__global__ __launch_bounds__(256, 1) void k_gru(
    const int* __restrict__ Mt, const int* __restrict__ schars_T,
    const _Float16* __restrict__ embp, const _Float16* __restrict__ Wp,
    const float* __restrict__ b_ih, const float* __restrict__ b_hh,
    _Float16* __restrict__ hq0, _Float16* __restrict__ hq1,
    const int* __restrict__ iperm, float* __restrict__ out,
    int* __restrict__ bar) {
  __shared__ __attribute__((aligned(16))) _Float16 As[64][512];   // 64 KB
  __shared__ __attribute__((aligned(16))) _Float16 Hs[64][68];    // 8.7 KB

  int bid = blockIdx.x;
  int rb = bid & 31, cb = bid >> 5;
  int m0 = rb * 64;
  int tid = threadIdx.x;
  int w = tid >> 6;
  int l = tid & 63;
  int ln = l & 15, kc = l >> 4;

  half8 wfr[54];
  const _Float16* wsrc = Wp + ((size_t)(cb * 18) * 12 + w * 3) * 512 + l * 8;
  #pragma unroll
  for (int c = 0; c < 18; ++c) {
    #pragma unroll
    for (int g = 0; g < 3; ++g)
      wfr[c * 3 + g] = *(const half8*)(wsrc + (c * 12 + g) * 512);
  }

  int colg = cb * 64 + w * 16 + ln;
  float br  = b_ih[colg] + b_hh[colg];
  float bz  = b_ih[H_ + colg] + b_hh[H_ + colg];
  float bnx = b_ih[2 * H_ + colg];
  float bnh = b_hh[2 * H_ + colg];

  float hreg[4][4];
  #pragma unroll
  for (int i = 0; i < 4; ++i)
    #pragma unroll
    for (int j = 0; j < 4; ++j) hreg[i][j] = 0.0f;

  int* barp = bar + rb * 32;

  for (int t = 0; t < T_; ++t) {
    int M = Mt[t];
    if (m0 >= M) break;
    const _Float16* hin = (t & 1) ? hq1 : hq0;
    _Float16*       hout = (t & 1) ? hq0 : hq1;

    int ch[4];
    #pragma unroll
    for (int rf = 0; rf < 4; ++rf)
      ch[rf] = schars_T[t * B_ + m0 + rf * 16 + ln];

    u64 sb[16][2];
    if (MODE == 1 || MODE == 4) {
      #pragma unroll
      for (int i = 0; i < 16; ++i) { sb[i][0] = 0; sb[i][1] = 0; }
    }
    if (t > 0) {
      if (MODE == 0 || MODE == 1) {
        if (tid == 0) {
          int target = 8 * t;
          while (__hip_atomic_load(barp, __ATOMIC_RELAXED, __HIP_MEMORY_SCOPE_AGENT) < target) {}
        }
      }
      __syncthreads();
      if (MODE == 0 || MODE == 2) {
        #pragma unroll
        for (int i = 0; i < 16; ++i) {
          int r = w * 16 + i;
          u64* src = (u64*)(hin + (size_t)(m0 + r) * H_) + ((l ^ (i & 7)) << 1);
          sb[i][0] = __hip_atomic_load(src, __ATOMIC_RELAXED, __HIP_MEMORY_SCOPE_AGENT);
          sb[i][1] = __hip_atomic_load(src + 1, __ATOMIC_RELAXED, __HIP_MEMORY_SCOPE_AGENT);
        }
      } else if (MODE == 3) {
        #pragma unroll
        for (int i = 0; i < 16; ++i) {
          int r = w * 16 + i;
          const u64* src = (const u64*)(hin + (size_t)(m0 + r) * H_) + ((l ^ (i & 7)) << 1);
          sb[i][0] = src[0];
          sb[i][1] = src[1];
        }
      }
    }

    f32x4 accr[4], accz[4], accnx[4], accnh[4];
    #pragma unroll
    for (int i = 0; i < 4; ++i) {
      accr[i] = (f32x4){0.f, 0.f, 0.f, 0.f};
      accz[i] = (f32x4){0.f, 0.f, 0.f, 0.f};
      accnx[i] = (f32x4){0.f, 0.f, 0.f, 0.f};
      accnh[i] = (f32x4){0.f, 0.f, 0.f, 0.f};
    }

    #pragma unroll
    for (int rf = 0; rf < 4; ++rf) {
      const _Float16* ep = embp + ch[rf] * E_ + kc * 8;
      half8 a0 = *(const half8*)ep;
      half8 a1 = *(const half8*)(ep + 32);
      accr[rf]  = mf16(a0, wfr[0], accr[rf]);
      accz[rf]  = mf16(a0, wfr[1], accz[rf]);
      accnx[rf] = mf16(a0, wfr[2], accnx[rf]);
      accr[rf]  = mf16(a1, wfr[3], accr[rf]);
      accz[rf]  = mf16(a1, wfr[4], accz[rf]);
      accnx[rf] = mf16(a1, wfr[5], accnx[rf]);
    }

    if (t > 0) {
      #pragma unroll
      for (int i = 0; i < 16; ++i) {
        int r = w * 16 + i;
        u64* dp = (u64*)&As[r][l * 8];
        dp[0] = sb[i][0];
        dp[1] = sb[i][1];
      }
    }
    __syncthreads();

    if (t > 0) {
      const _Float16* asb = &As[0][0];
      #pragma unroll
      for (int chk = 0; chk < 16; ++chk) {
        #pragma unroll
        for (int rf = 0; rf < 4; ++rf) {
          int r = rf * 16 + ln;
          half8 af = *(const half8*)(asb + r * 512 + (((chk * 4 + kc) ^ (ln & 7)) << 3));
          accr[rf]  = mf16(af, wfr[(chk + 2) * 3 + 0], accr[rf]);
          accz[rf]  = mf16(af, wfr[(chk + 2) * 3 + 1], accz[rf]);
          accnh[rf] = mf16(af, wfr[(chk + 2) * 3 + 2], accnh[rf]);
        }
      }
    }

    #pragma unroll
    for (int rf = 0; rf < 4; ++rf) {
      #pragma unroll
      for (int q = 0; q < 4; ++q) {
        int row_l = rf * 16 + kc * 4 + q;
        if (m0 + row_l < M) {
          float r_ = sigmoidf_(accr[rf][q] + br);
          float z_ = sigmoidf_(accz[rf][q] + bz);
          float n_ = tanh_fast(accnx[rf][q] + bnx + r_ * (accnh[rf][q] + bnh));
          float hnew = (1.0f - z_) * n_ + z_ * hreg[rf][q];
          hreg[rf][q] = hnew;
          Hs[row_l][w * 16 + ln] = (_Float16)hnew;
        }
      }
    }
    __syncthreads();

    if (MODE != 4) {
      #pragma unroll
      for (int j = 0; j < 4; ++j) {
        int c = tid + 256 * j;
        int row_l = c >> 4;
        int coff = (c & 15) * 4;
        if (m0 + row_l < M) {
          u64 v = *(const u64*)&Hs[row_l][coff];
          u64* gp = (u64*)(hout + (size_t)(m0 + row_l) * H_ + cb * 64 + coff);
          if (MODE == 3) *gp = v;
          else __hip_atomic_store(gp, v, __ATOMIC_RELAXED, __HIP_MEMORY_SCOPE_AGENT);
        }
      }
      asm volatile("s_waitcnt vmcnt(0)" ::: "memory");
      __syncthreads();
      if (tid == 0) {
        if (MODE == 3) {
          barp[0] = t + 1;   // plain store, nobody polls in MODE 3
        } else {
          __hip_atomic_fetch_add(barp, 1, __ATOMIC_RELAXED, __HIP_MEMORY_SCOPE_AGENT);
        }
      }
    } else {
      // MODE 4: keep Hs alive without global traffic (rule #17)
      #pragma unroll
      for (int j = 0; j < 4; ++j) {
        int c = tid + 256 * j;
        u64 v = *(const u64*)&Hs[c >> 4][(c & 15) * 4];
        asm volatile("" :: "v"(v));
      }
      __syncthreads();
    }
  }

  #pragma unroll
  for (int rf = 0; rf < 4; ++rf) {
    #pragma unroll
    for (int q = 0; q < 4; ++q) {
      int row = m0 + rf * 16 + kc * 4 + q;
      out[(size_t)iperm[row] * H_ + colg] = hreg[rf][q];
    }
  }
}

extern "C" void kernel_launch(void* const* d_in, const int* in_sizes, int n_in,
                              void* d_out, int out_size, void* d_ws, size_t ws_size,
                              hipStream_t stream) {
  const int*   data = (const int*)d_in[0];
  const int*   st   = (const int*)d_in[1];
  const float* emb  = (const float*)d_in[2];
  const float* W_ih = (const float*)d_in[3];
  const float* W_hh = (const float*)d_in[4];
  const float* b_ih = (const float*)d_in[5];
  const float* b_hh = (const float*)d_in[6];
  float* out = (float*)d_out;

  // workspace (~14.4 MB)
  _Float16* hq0  = (_Float16*)d_ws;                 // B*H
  _Float16* hq1  = hq0 + B_ * H_;                   // B*H
  _Float16* Wp   = hq1 + B_ * H_;                   // 884736
  _Float16* embp = Wp + 8 * 18 * 12 * 512;          // 8192
  int* perm   = (int*)(embp + 128 * E_);
  int* iperm  = perm + B_;
  int* Mt     = iperm + B_;
  int* flags  = Mt + 32;                            // 4096 ints (4 x 1024)
  int* schars = flags + 4096;                       // B*T
  _Float16* sA   = (_Float16*)(schars + B_ * T_);   // scratch h pair
  _Float16* sB   = sA + B_ * H_;
  float*    sout = (float*)(sB + B_ * H_);          // scratch out

  k_setup<<<1, 256, 0, stream>>>(data, st, perm, iperm, Mt, flags);
  k_schars<<<(B_ * T_ + 255) / 256, 256, 0, stream>>>(data, st, perm, schars);
  k_wconv<<<(8 * 18 * 12 * 512 + 255) / 256, 256, 0, stream>>>(W_ih, W_hh, Wp);
  k_embconv<<<(128 * E_ + 255) / 256, 256, 0, stream>>>(emb, embp);

  // real (round-8 exact)
  k_gru<0><<<dim3(256), dim3(256), 0, stream>>>(Mt, schars, embp, Wp, b_ih, b_hh,
                                                hq0, hq1, iperm, out, flags);
  // ablations (scratch only)
  k_gru<1><<<dim3(256), dim3(256), 0, stream>>>(Mt, schars, embp, Wp, b_ih, b_hh,
                                                sA, sB, iperm, sout, flags + 1024);
  k_gru<2><<<dim3(256), dim3(256), 0, stream>>>(Mt, schars, embp, Wp, b_ih, b_hh,
                                                sA, sB, iperm, sout, flags + 2048);
  k_gru<3><<<dim3(256), dim3(256), 0, stream>>>(Mt, schars, embp, Wp, b_ih, b_hh,
                                                sA, sB, iperm, sout, flags + 3072);
  k_gru<4><<<dim3(256), dim3(256), 0, stream>>>(Mt, schars, embp, Wp, b_ih, b_hh,
                                                sA, sB, iperm, sout, flags + 3072);
}

// Round 14
// 229.896 us; speedup vs baseline: 3.4315x; 3.4315x over previous
//
#include <hip/hip_runtime.h>
#include <hip/hip_bf16.h>
#include <math.h>

#define B_  2048
#define E_  64
#define H_  512
#define T_  20

typedef _Float16 half8 __attribute__((ext_vector_type(8)));
typedef __attribute__((ext_vector_type(4))) float f32x4;
typedef unsigned long long u64;

#define mf16(a, b, c) __builtin_amdgcn_mfma_f32_16x16x32_f16(a, b, c, 0, 0, 0)

__device__ __forceinline__ float sigmoidf_(float x) {
  return 1.0f / (1.0f + __expf(-x));
}
__device__ __forceinline__ float tanh_fast(float x) {
  float e = __expf(2.0f * x);
  return 1.0f - 2.0f / (e + 1.0f);
}

// ---------------------------------------------------------------------------
// Parallel stable counting sort + inverse perm + zero flag area.
// ---------------------------------------------------------------------------
__global__ __launch_bounds__(256) void k_setup(const int* __restrict__ data,
                                               const int* __restrict__ st,
                                               int* __restrict__ perm,
                                               int* __restrict__ iperm,
                                               int* __restrict__ Mt,
                                               int* __restrict__ flags) {
  __shared__ int lens[B_];
  __shared__ int hist[256][22];
  __shared__ int sub[16][22];
  __shared__ int subpre[16][22];
  __shared__ int cnt[32];
  __shared__ int offs[32];
  int tid = threadIdx.x;

  #pragma unroll
  for (int i = 0; i < 4; ++i) flags[tid * 4 + i] = 0;

  #pragma unroll
  for (int q = 0; q < 8; ++q) {
    int i = tid * 8 + q;
    lens[i] = st[data[i] * (T_ + 1) + T_];
  }
  #pragma unroll
  for (int L = 0; L < 22; ++L) hist[tid][L] = 0;
  #pragma unroll
  for (int q = 0; q < 8; ++q) hist[tid][lens[tid * 8 + q]]++;
  __syncthreads();

  for (int q = tid; q < 16 * 21; q += 256) {
    int g = q / 21, L = q % 21;
    int run = 0;
    for (int j = 0; j < 16; ++j) {
      int v = hist[g * 16 + j][L];
      hist[g * 16 + j][L] = run;
      run += v;
    }
    sub[g][L] = run;
  }
  __syncthreads();
  if (tid < 21) {
    int run = 0;
    for (int g = 0; g < 16; ++g) { subpre[g][tid] = run; run += sub[g][tid]; }
    cnt[tid] = run;
  }
  __syncthreads();
  if (tid <= 20) {
    int s = 0;
    for (int L = tid + 1; L <= 20; ++L) s += cnt[L];
    offs[tid] = s;
  }
  __syncthreads();
  if (tid < T_) Mt[tid] = offs[tid];
  if (tid >= T_ && tid < 32) Mt[tid] = 0;

  int g = tid >> 4;
  #pragma unroll
  for (int q = 0; q < 8; ++q) {
    int i = tid * 8 + q;
    int L = lens[i];
    int rk = subpre[g][L] + hist[tid][L];
    hist[tid][L] += 1;
    perm[offs[L] + rk] = i;
  }
  __syncthreads();
  #pragma unroll
  for (int q = 0; q < 8; ++q) {
    int i = tid * 8 + q;
    iperm[perm[i]] = i;
  }
}

__global__ void k_schars(const int* __restrict__ data, const int* __restrict__ st,
                         const int* __restrict__ perm, int* __restrict__ schars_T) {
  int idx = blockIdx.x * 256 + threadIdx.x;
  if (idx >= B_ * T_) return;
  int t = idx >> 11;
  int j = idx & (B_ - 1);
  schars_T[idx] = st[data[perm[j]] * (T_ + 1) + t];
}

// W_hh -> fp16 fragment-packed: Wp[(((cb*16+c)*4+w)*3+g)*512 + l*8 + e]
__global__ void k_wconv(const float* __restrict__ W_hh, _Float16* __restrict__ Wp) {
  int idx = blockIdx.x * 256 + threadIdx.x;
  if (idx >= 8 * 16 * 12 * 512) return;
  int e = idx & 7;
  int l = (idx >> 3) & 63;
  int rest = idx >> 9;
  int g = rest % 3;  rest /= 3;
  int wc = rest & 3; rest >>= 2;
  int c = rest % 16;
  int cb = rest / 16;
  int grow = g * H_ + cb * 64 + wc * 16 + (l & 15);
  int k = c * 32 + (l >> 4) * 8 + e;
  Wp[idx] = (_Float16)W_hh[grow * H_ + k];
}

// embW[c][g*512+col] = emb[c] . W_ih[g*512+col] + b_ih (+ b_hh for r,z)
__global__ __launch_bounds__(256) void k_embw(const float* __restrict__ emb,
                                              const float* __restrict__ W_ih,
                                              const float* __restrict__ b_ih,
                                              const float* __restrict__ b_hh,
                                              float* __restrict__ embW) {
  int c = blockIdx.x;
  int tid = threadIdx.x;
  __shared__ float ev[64];
  if (tid < 64) ev[tid] = emb[c * E_ + tid];
  __syncthreads();
  for (int o = tid; o < 3 * H_; o += 256) {
    float s = b_ih[o];
    if (o < 2 * H_) s += b_hh[o];
    #pragma unroll
    for (int k = 0; k < E_; ++k) s = fmaf(ev[k], W_ih[o * E_ + k], s);
    embW[(size_t)c * (3 * H_) + o] = s;
  }
}

// ---------------------------------------------------------------------------
// Persistent GRU, W STREAMED from L2 (no resident W registers -> nothing for
// the compiler to rematerialize). r8 exchange/staging/store/flag protocol.
// Depth-2 group pipeline: 4 groups x 4 chunks; issue group g+1 before
// computing group g; sched_barrier(0) between groups caps in-flight W at
// 24 frags (96 VGPR). x-side folded into embW table (r11, proven).
// ---------------------------------------------------------------------------
__global__ __launch_bounds__(256, 1) void k_gru(
    const int* __restrict__ Mt, const int* __restrict__ schars_T,
    const float* __restrict__ embW, const _Float16* __restrict__ Wp,
    const float* __restrict__ b_hh,
    _Float16* __restrict__ hq0, _Float16* __restrict__ hq1,
    const int* __restrict__ iperm, float* __restrict__ out,
    int* __restrict__ bar) {
  __shared__ __attribute__((aligned(16))) _Float16 As[64][512];   // 64 KB
  __shared__ __attribute__((aligned(16))) _Float16 Hs[64][68];    // 8.7 KB

  int bid = blockIdx.x;
  int rb = bid & 31, cb = bid >> 5;
  int m0 = rb * 64;
  int tid = threadIdx.x;
  int w = tid >> 6;
  int l = tid & 63;
  int ln = l & 15, kc = l >> 4;

  int colg = cb * 64 + w * 16 + ln;
  float bnh = b_hh[2 * H_ + colg];

  float hreg[4][4];
  #pragma unroll
  for (int i = 0; i < 4; ++i)
    #pragma unroll
    for (int j = 0; j < 4; ++j) hreg[i][j] = 0.0f;

  int* barp = bar + rb * 32;

// W fragment load for h-chunk c, gate g (coalesced 1KB/wave, L2-resident)
#define WLOAD(c, g) (*(const half8*)(Wp + \
    (((size_t)(cb * 16 + (c)) * 4 + w) * 3 + (g)) * 512 + l * 8))

// MFMA for h-chunk c using frag array F with base chunk FB
#define H_CHUNK(c, F, FB)                                                      \
  {                                                                            \
    _Pragma("unroll")                                                          \
    for (int rf = 0; rf < 4; ++rf) {                                           \
      int r = rf * 16 + ln;                                                    \
      half8 af = *(const half8*)((const _Float16*)As + r * 512 +               \
                                 ((((c) * 4 + kc) ^ (ln & 7)) << 3));          \
      accr[rf]  = mf16(af, F[((c) - (FB)) * 3 + 0], accr[rf]);                 \
      accz[rf]  = mf16(af, F[((c) - (FB)) * 3 + 1], accz[rf]);                 \
      accnh[rf] = mf16(af, F[((c) - (FB)) * 3 + 2], accnh[rf]);                \
    }                                                                          \
  }

  for (int t = 0; t < T_; ++t) {
    int M = Mt[t];
    if (m0 >= M) break;
    const _Float16* hin = (t & 1) ? hq1 : hq0;
    _Float16*       hout = (t & 1) ? hq0 : hq1;

    // chars for this step's epilogue embW lookup (own output rows)
    int chv[4][4];
    #pragma unroll
    for (int rf = 0; rf < 4; ++rf)
      #pragma unroll
      for (int q = 0; q < 4; ++q)
        chv[rf][q] = schars_T[t * B_ + m0 + rf * 16 + kc * 4 + q];

    f32x4 accr[4], accz[4], accnh[4];
    #pragma unroll
    for (int i = 0; i < 4; ++i) {
      accr[i] = (f32x4){0.f, 0.f, 0.f, 0.f};
      accz[i] = (f32x4){0.f, 0.f, 0.f, 0.f};
      accnh[i] = (f32x4){0.f, 0.f, 0.f, 0.f};
    }

    if (t > 0) {
      // ---- wait for cohort, then stage h (r8 exact) ----
      if (tid == 0) {
        int target = 8 * t;
        while (__hip_atomic_load(barp, __ATOMIC_RELAXED, __HIP_MEMORY_SCOPE_AGENT) < target) {}
      }
      __syncthreads();
      u64 sb[16][2];
      #pragma unroll
      for (int i = 0; i < 16; ++i) {
        int r = w * 16 + i;
        u64* src = (u64*)(hin + (size_t)(m0 + r) * H_) + ((l ^ (i & 7)) << 1);
        sb[i][0] = __hip_atomic_load(src, __ATOMIC_RELAXED, __HIP_MEMORY_SCOPE_AGENT);
        sb[i][1] = __hip_atomic_load(src + 1, __ATOMIC_RELAXED, __HIP_MEMORY_SCOPE_AGENT);
      }

      // ---- issue W groups 0,1 while sb is in flight ----
      half8 wfA[12], wfB[12];
      #pragma unroll
      for (int cc = 0; cc < 4; ++cc)
        #pragma unroll
        for (int g = 0; g < 3; ++g) {
          wfA[cc * 3 + g] = WLOAD(cc, g);
          wfB[cc * 3 + g] = WLOAD(4 + cc, g);
        }

      // ---- drain sb into As (linear dest; src was pre-swizzled) ----
      #pragma unroll
      for (int i = 0; i < 16; ++i) {
        int r = w * 16 + i;
        u64* dp = (u64*)&As[r][l * 8];
        dp[0] = sb[i][0];
        dp[1] = sb[i][1];
      }
      __syncthreads();

      // ---- group-pipelined K loop: compute G(g), issue G(g+2) ----
      // G0
      H_CHUNK(0, wfA, 0) H_CHUNK(1, wfA, 0) H_CHUNK(2, wfA, 0) H_CHUNK(3, wfA, 0)
      __builtin_amdgcn_sched_barrier(0);
      #pragma unroll
      for (int cc = 0; cc < 4; ++cc)
        #pragma unroll
        for (int g = 0; g < 3; ++g)
          wfA[cc * 3 + g] = WLOAD(8 + cc, g);
      // G1
      H_CHUNK(4, wfB, 4) H_CHUNK(5, wfB, 4) H_CHUNK(6, wfB, 4) H_CHUNK(7, wfB, 4)
      __builtin_amdgcn_sched_barrier(0);
      #pragma unroll
      for (int cc = 0; cc < 4; ++cc)
        #pragma unroll
        for (int g = 0; g < 3; ++g)
          wfB[cc * 3 + g] = WLOAD(12 + cc, g);
      // G2
      H_CHUNK(8, wfA, 8) H_CHUNK(9, wfA, 8) H_CHUNK(10, wfA, 8) H_CHUNK(11, wfA, 8)
      __builtin_amdgcn_sched_barrier(0);
      // G3
      H_CHUNK(12, wfB, 12) H_CHUNK(13, wfB, 12) H_CHUNK(14, wfB, 12) H_CHUNK(15, wfB, 12)
    } else {
      __syncthreads();
    }

    // ---- epilogue: embW lookup + gates -> hreg; fp16 into Hs tile ----
    #pragma unroll
    for (int rf = 0; rf < 4; ++rf) {
      #pragma unroll
      for (int q = 0; q < 4; ++q) {
        int row_l = rf * 16 + kc * 4 + q;
        if (m0 + row_l < M) {
          const float* ew = embW + (size_t)chv[rf][q] * (3 * H_) + colg;
          float r_ = sigmoidf_(accr[rf][q] + ew[0]);
          float z_ = sigmoidf_(accz[rf][q] + ew[H_]);
          float n_ = tanh_fast(ew[2 * H_] + r_ * (accnh[rf][q] + bnh));
          float hnew = (1.0f - z_) * n_ + z_ * hreg[rf][q];
          hreg[rf][q] = hnew;
          Hs[row_l][w * 16 + ln] = (_Float16)hnew;
        }
      }
    }
    __syncthreads();

    // ---- coalesced agent-scope h-out (r8 exact) ----
    #pragma unroll
    for (int j = 0; j < 4; ++j) {
      int c = tid + 256 * j;
      int row_l = c >> 4;
      int coff = (c & 15) * 4;
      if (m0 + row_l < M) {
        u64 v = *(const u64*)&Hs[row_l][coff];
        __hip_atomic_store((u64*)(hout + (size_t)(m0 + row_l) * H_ + cb * 64 + coff),
                           v, __ATOMIC_RELAXED, __HIP_MEMORY_SCOPE_AGENT);
      }
    }
    asm volatile("s_waitcnt vmcnt(0)" ::: "memory");
    __syncthreads();
    if (tid == 0)
      __hip_atomic_fetch_add(barp, 1, __ATOMIC_RELAXED, __HIP_MEMORY_SCOPE_AGENT);
  }
#undef H_CHUNK
#undef WLOAD

  // ---- final state -> out[iperm[row]] (reference returns ht[perm]) ----
  #pragma unroll
  for (int rf = 0; rf < 4; ++rf) {
    #pragma unroll
    for (int q = 0; q < 4; ++q) {
      int row = m0 + rf * 16 + kc * 4 + q;
      out[(size_t)iperm[row] * H_ + colg] = hreg[rf][q];
    }
  }
}

extern "C" void kernel_launch(void* const* d_in, const int* in_sizes, int n_in,
                              void* d_out, int out_size, void* d_ws, size_t ws_size,
                              hipStream_t stream) {
  const int*   data = (const int*)d_in[0];
  const int*   st   = (const int*)d_in[1];
  const float* emb  = (const float*)d_in[2];
  const float* W_ih = (const float*)d_in[3];
  const float* W_hh = (const float*)d_in[4];
  const float* b_ih = (const float*)d_in[5];
  const float* b_hh = (const float*)d_in[6];
  float* out = (float*)d_out;

  // workspace (~7 MB)
  _Float16* hq0  = (_Float16*)d_ws;                 // B*H fp16
  _Float16* hq1  = hq0 + B_ * H_;                   // B*H fp16
  _Float16* Wp   = hq1 + B_ * H_;                   // 786432 halfs
  float*    embW = (float*)(Wp + 8 * 16 * 12 * 512);// 128*1536 fp32
  int* perm   = (int*)(embW + 128 * 3 * H_);
  int* iperm  = perm + B_;
  int* Mt     = iperm + B_;
  int* flags  = Mt + 32;                            // 1024 ints
  int* schars = flags + 1024;

  k_setup<<<1, 256, 0, stream>>>(data, st, perm, iperm, Mt, flags);
  k_schars<<<(B_ * T_ + 255) / 256, 256, 0, stream>>>(data, st, perm, schars);
  k_wconv<<<(8 * 16 * 12 * 512 + 255) / 256, 256, 0, stream>>>(W_hh, Wp);
  k_embw<<<128, 256, 0, stream>>>(emb, W_ih, b_ih, b_hh, embW);

  k_gru<<<dim3(256), dim3(256), 0, stream>>>(Mt, schars, embW, Wp, b_hh,
                                             hq0, hq1, iperm, out, flags);
}